// Round 1
// baseline (412.436 us; speedup 1.0000x reference)
//
#include <hip/hip_runtime.h>
#include <math.h>

#define NPTS 4096
#define CH 4
#define CHN 1024
#define EPSC 1e-5f
#define FACTC 2.0f

// ws layout (float offsets)
#define OFF_PACK  0         // float4[8*4096]            = 131072 floats
#define OFF_PART  131072    // [8][4][5][4096]           = 655360 floats
#define OFF_PCN   786432    // [8][3][4096]              =  98304 floats
#define OFF_DIST  884736    // [8][4096]                 =  32768 floats
#define OFF_STATS 917504    // [8][16]                   =    128 floats
#define OFF_ASUM  917632    // [8][40]                   =    320 floats
// total ~3.6 MB of workspace

__global__ void __launch_bounds__(256) k_pack(const float* __restrict__ pc2,
                                              float4* __restrict__ pack){
  int idx = blockIdx.x*256 + threadIdx.x;           // 32768 threads
  int b = idx >> 12, m = idx & 4095;
  const float* p = pc2 + (size_t)b*4*NPTS + m;
  float x = p[0], y = p[NPTS], z = p[2*NPTS];
  pack[idx] = make_float4(x, y, z, x*x + y*y + z*z);
}

// one thread = one pc1 row; one block = (sample, 256-row block, 1024-col chunk)
__global__ void __launch_bounds__(256) k_soft(const float* __restrict__ pc1,
                                              const float4* __restrict__ pack,
                                              float* __restrict__ part){
  int bid = blockIdx.x;                              // 512 blocks
  int chunk = bid & 3, rb = (bid >> 2) & 15, b = bid >> 6;
  int n = rb*256 + threadIdx.x;
  const float* p1 = pc1 + (size_t)b*4*NPTS + n;
  float x1 = p1[0], y1 = p1[NPTS], z1 = p1[2*NPTS];
  float q1 = x1*x1 + y1*y1 + z1*z1;
  const float4* cp = pack + b*NPTS + chunk*CHN;      // uniform address -> s_load
  // pass 1: min distance (max score)
  float dmin = 3.4e38f;
  #pragma unroll 8
  for (int m=0; m<CHN; ++m){
    float4 c = cp[m];
    float dot = fmaf(x1,c.x,fmaf(y1,c.y,z1*c.z));
    float d = fmaf(-2.f,dot,q1) + c.w;
    dmin = fminf(dmin, d);
  }
  float smax = FACTC * __builtin_amdgcn_rcpf(fmaxf(dmin, EPSC));
  // pass 2: exp-sum + weighted value accumulation
  float L=0.f, Ax=0.f, Ay=0.f, Az=0.f;
  #pragma unroll 4
  for (int m=0; m<CHN; ++m){
    float4 c = cp[m];
    float dot = fmaf(x1,c.x,fmaf(y1,c.y,z1*c.z));
    float d = fmaf(-2.f,dot,q1) + c.w;
    float s = FACTC * __builtin_amdgcn_rcpf(fmaxf(d, EPSC));
    float pe = __expf(s - smax);
    L += pe;
    Ax = fmaf(pe,c.x,Ax); Ay = fmaf(pe,c.y,Ay); Az = fmaf(pe,c.z,Az);
  }
  float* pp = part + ((size_t)(b*CH + chunk)*5)*NPTS + n;
  pp[0]=smax; pp[NPTS]=L; pp[2*NPTS]=Ax; pp[3*NPTS]=Ay; pp[4*NPTS]=Az;
}

// merge chunk partials -> pc_nearest + dist; fused per-sample stats
__global__ void __launch_bounds__(256) k_merge(const float* __restrict__ pc1,
                                               const float* __restrict__ part,
                                               float* __restrict__ pcn,
                                               float* __restrict__ dist,
                                               float* __restrict__ stats){
  int b = blockIdx.x, t = threadIdx.x;               // 8 blocks
  float acc[13];
  #pragma unroll
  for (int k=0;k<13;k++) acc[k]=0.f;
  for (int i=0;i<16;i++){
    int n = i*256 + t;
    float sc[4], Lc[4], Axc[4], Ayc[4], Azc[4];
    float S = -3.4e38f;
    #pragma unroll
    for (int c=0;c<4;c++){
      const float* pp = part + ((size_t)(b*4+c)*5)*NPTS + n;
      sc[c]=pp[0]; Lc[c]=pp[NPTS]; Axc[c]=pp[2*NPTS]; Ayc[c]=pp[3*NPTS]; Azc[c]=pp[4*NPTS];
      S = fmaxf(S, sc[c]);
    }
    float L=0.f, Ax=0.f, Ay=0.f, Az=0.f;
    #pragma unroll
    for (int c=0;c<4;c++){
      float w = __expf(sc[c]-S);
      L=fmaf(w,Lc[c],L); Ax=fmaf(w,Axc[c],Ax); Ay=fmaf(w,Ayc[c],Ay); Az=fmaf(w,Azc[c],Az);
    }
    float inv = 1.f/L;
    float px=Ax*inv, py=Ay*inv, pz=Az*inv;
    const float* p1 = pc1 + (size_t)b*4*NPTS + n;
    float x1=p1[0], y1=p1[NPTS], z1=p1[2*NPTS];
    float dx=x1-px, dy=y1-py, dz=z1-pz;
    float dd=sqrtf(dx*dx+dy*dy+dz*dz);
    pcn[(size_t)(b*3+0)*NPTS+n]=px;
    pcn[(size_t)(b*3+1)*NPTS+n]=py;
    pcn[(size_t)(b*3+2)*NPTS+n]=pz;
    dist[(size_t)b*NPTS+n]=dd;
    acc[0]+=x1;    acc[1]+=y1;    acc[2]+=z1;
    acc[3]+=x1*x1; acc[4]+=y1*y1; acc[5]+=z1*z1;
    acc[6]+=px;    acc[7]+=py;    acc[8]+=pz;
    acc[9]+=px*px; acc[10]+=py*py; acc[11]+=pz*pz;
    acc[12]+=dd;
  }
  __shared__ float red[4][13];
  int lane = t & 63, wv = t >> 6;
  #pragma unroll
  for (int k=0;k<13;k++){
    float v = acc[k];
    v += __shfl_xor(v,32); v += __shfl_xor(v,16); v += __shfl_xor(v,8);
    v += __shfl_xor(v,4);  v += __shfl_xor(v,2);  v += __shfl_xor(v,1);
    if (lane==0) red[wv][k]=v;
  }
  __syncthreads();
  if (t==0){
    float tot[13];
    #pragma unroll
    for (int k=0;k<13;k++) tot[k]=red[0][k]+red[1][k]+red[2][k]+red[3][k];
    const float Nf = 4096.f, Nm1 = 4095.f;
    float st[13];
    #pragma unroll
    for (int j=0;j<3;j++){
      float m  = tot[j]/Nf;
      float v  = (tot[3+j]-Nf*m*m)/Nm1;      // ddof=1
      st[j]=m; st[3+j]=sqrtf(fmaxf(v,0.f));
      float m2 = tot[6+j]/Nf;
      float v2 = (tot[9+j]-Nf*m2*m2)/Nm1;
      st[6+j]=m2; st[9+j]=sqrtf(fmaxf(v2,0.f));
    }
    st[12]=tot[12]/Nf;
    #pragma unroll
    for (int k=0;k<13;k++) stats[b*16+k]=st[k];
  }
}

// accumulate the 4 weighted aa^T blocks of A = M^T M  (40 sums per sample)
__global__ void __launch_bounds__(256) k_accum(const float* __restrict__ pc1,
                                               const float* __restrict__ pcn,
                                               const float* __restrict__ dist,
                                               const float* __restrict__ stats,
                                               float* __restrict__ asums){
  int b=blockIdx.x, t=threadIdx.x;                   // 8 blocks
  const float* st = stats + b*16;
  float i1x=1.f/st[3], i1y=1.f/st[4], i1z=1.f/st[5];
  float t1x=-st[0]/st[3], t1y=-st[1]/st[4], t1z=-st[2]/st[5];
  float i2x=1.f/st[9], i2y=1.f/st[10], i2z=1.f/st[11];
  float t2x=-st[6]/st[9], t2y=-st[7]/st[10], t2z=-st[8]/st[11];
  float meanD=st[12];
  float acc[40];
  #pragma unroll
  for (int k=0;k<40;k++) acc[k]=0.f;
  for (int i=0;i<16;i++){
    int n=i*256+t;
    const float* p1 = pc1 + (size_t)b*4*NPTS + n;
    float X1=fmaf(p1[0],i1x,t1x), Y1=fmaf(p1[NPTS],i1y,t1y), Z1=fmaf(p1[2*NPTS],i1z,t1z);
    float X2=fmaf(pcn[(size_t)(b*3+0)*NPTS+n],i2x,t2x);
    float Y2=fmaf(pcn[(size_t)(b*3+1)*NPTS+n],i2y,t2y);
    float Z2=fmaf(pcn[(size_t)(b*3+2)*NPTS+n],i2z,t2z);
    // sigmoid((dist-mean-EPS)*-1e10) > 0.5  <=>  (dist-mean)-EPS < 0
    float zthr = (dist[(size_t)b*NPTS+n] - meanD) - EPSC;
    float msk = (zthr < 0.f) ? 1.f : 0.f;
    float tz = msk*Z2;
    float wA = tz*Z2, wB = -tz*X2, wC = -tz*Y2;
    float wD = msk*fmaf(X2,X2,Y2*Y2);
    float ee[10]={X1*X1, X1*Y1, X1*Z1, X1, Y1*Y1, Y1*Z1, Y1, Z1*Z1, Z1, 1.f};
    #pragma unroll
    for (int j=0;j<10;j++){
      acc[j]    = fmaf(wA,ee[j],acc[j]);
      acc[10+j] = fmaf(wB,ee[j],acc[10+j]);
      acc[20+j] = fmaf(wC,ee[j],acc[20+j]);
      acc[30+j] = fmaf(wD,ee[j],acc[30+j]);
    }
  }
  __shared__ float red[4][40];
  int lane=t&63, wv=t>>6;
  #pragma unroll
  for (int k=0;k<40;k++){
    float v=acc[k];
    v+=__shfl_xor(v,32); v+=__shfl_xor(v,16); v+=__shfl_xor(v,8);
    v+=__shfl_xor(v,4);  v+=__shfl_xor(v,2);  v+=__shfl_xor(v,1);
    if(lane==0) red[wv][k]=v;
  }
  __syncthreads();
  if (t<40) asums[b*40+t]=red[0][t]+red[1][t]+red[2][t]+red[3][t];
}

__device__ __forceinline__ float elemA(const float* S, int i, int k){
  int bi=i>>2, bj=k>>2;
  int ii=i&3, jj=k&3;
  int lo = ii<jj?ii:jj, hi = ii<jj?jj:ii;
  int pe = 4*lo - ((lo*(lo-1))>>1) + (hi-lo);        // sym 4x4 -> 10 idx
  int w;
  if (bi==bj) w = (bi==2)?30:0;
  else {
    int blo = bi<bj?bi:bj, bhi = bi<bj?bj:bi;
    if (blo==0 && bhi==1) return 0.f;                // A01 block is zero
    w = (blo==0)?10:20;                              // (0,2)->wB, (1,2)->wC
  }
  return S[w+pe];
}

// per-sample: 12x12 Jacobi eigensolve (lane-parallel, wave-synchronous) + compose
__global__ void __launch_bounds__(64) k_solve(const float* __restrict__ asums,
                                              const float* __restrict__ stats,
                                              float* __restrict__ out){
  int b=blockIdx.x, t=threadIdx.x;                   // 8 blocks x 1 wave
  __shared__ float A[12][13];
  __shared__ float V[12][13];
  const float* S = asums + b*40;
  if (t<12){
    #pragma unroll
    for (int i=0;i<12;i++){
      A[i][t]=elemA(S,i,t);
      V[i][t]=(i==t)?1.f:0.f;
    }
  }
  __builtin_amdgcn_wave_barrier();
  bool act = (t<12);
  for (int sweep=0; sweep<12; ++sweep){
    for (int r=0; r<11; ++r){
      // round-robin tournament pairing (circle method), 6 disjoint pairs
      int partner;
      if (t==0) partner = 1+r;
      else {
        int i = (t-1-r)%11; if (i<0) i+=11;
        partner = (i==0)?0:(1+(11-i+r)%11);
      }
      int p = t<partner?t:partner, q = t<partner?partner:t;
      float c=1.f, s=0.f;
      if (act){
        float apq=A[p][q];
        if (apq!=0.f){
          float tau=(A[q][q]-A[p][p])/(2.f*apq);
          float tt=1.f/(fabsf(tau)+sqrtf(fmaf(tau,tau,1.f)));
          if (tau<0.f) tt=-tt;
          c=1.f/sqrtf(fmaf(tt,tt,1.f));
          s=tt*c;
        }
      }
      float sg = (t==q)?s:-s;
      float na[12], nv[12];
      if (act){
        #pragma unroll
        for (int i=0;i<12;i++){
          na[i]=fmaf(c,A[i][t],sg*A[i][partner]);    // A <- A*J (columns)
          nv[i]=fmaf(c,V[i][t],sg*V[i][partner]);    // V <- V*J
        }
      }
      __builtin_amdgcn_wave_barrier();
      if (act){
        #pragma unroll
        for (int i=0;i<12;i++){ A[i][t]=na[i]; V[i][t]=nv[i]; }
      }
      __builtin_amdgcn_wave_barrier();
      if (act){
        #pragma unroll
        for (int j=0;j<12;j++) na[j]=fmaf(c,A[t][j],sg*A[partner][j]); // Jt*(AJ) rows
      }
      __builtin_amdgcn_wave_barrier();
      if (act){
        #pragma unroll
        for (int j=0;j<12;j++) A[t][j]=na[j];
      }
      __builtin_amdgcn_wave_barrier();
    }
  }
  if (t==0){
    float best=A[0][0]; int kb=0;
    #pragma unroll
    for (int i=1;i<12;i++){ if (A[i][i]<best){best=A[i][i];kb=i;} }
    double pv[12];
    #pragma unroll
    for (int i=0;i<12;i++) pv[i]=(double)V[i][kb];
    if (pv[10]<0.0){
      #pragma unroll
      for (int i=0;i<12;i++) pv[i]=-pv[i];
    }
    double nrm = sqrt(pv[8]*pv[8]+pv[9]*pv[9]+pv[10]*pv[10]);
    #pragma unroll
    for (int i=0;i<12;i++) pv[i]/=nrm;
    const float* st = stats + b*16;
    double m1[3]={st[0],st[1],st[2]}, sd1[3]={st[3],st[4],st[5]};
    double m2[3]={st[6],st[7],st[8]}, sd2[3]={st[9],st[10],st[11]};
    double Td[3][4]={{pv[0],pv[1],pv[2],pv[3]},
                     {pv[4],pv[5],pv[6],pv[7]},
                     {pv[8],pv[9],pv[10],pv[11]}};
    double F[3][4];
    for (int i=0;i<3;i++){
      double b3 = Td[i][3];
      for (int j=0;j<3;j++){
        F[i][j] = sd2[i]*(Td[i][j]/sd1[j]);          // inv(T2) @ Tdlt @ T1
        b3 += Td[i][j]*(-m1[j]/sd1[j]);
      }
      F[i][3] = sd2[i]*b3 + m2[i];
    }
    // normalize rotation: z=norm(col2); x=norm(cross(col1,z)); y=cross(z,x)
    double zx=F[0][2],zy=F[1][2],zz2=F[2][2];
    double zn=sqrt(zx*zx+zy*zy+zz2*zz2);
    zx/=zn; zy/=zn; zz2/=zn;
    double yx=F[0][1],yy=F[1][1],yz=F[2][1];
    double xx=yy*zz2-yz*zy, xy=yz*zx-yx*zz2, xz=yx*zy-yy*zx;
    double xn=sqrt(xx*xx+xy*xy+xz*xz);
    xx/=xn; xy/=xn; xz/=xn;
    double y2x=zy*xz-zz2*xy, y2y=zz2*xx-zx*xz, y2z=zx*xy-zy*xx;
    double R00=xx,R01=y2x,R02=zx;
    double R10=xy,R11=y2y,R12=zy;
    double R20=xz,R21=y2z,R22=zz2;
    float* oT = out + b*16;
    oT[0]=(float)R00; oT[1]=(float)R01; oT[2]=(float)R02; oT[3]=(float)F[0][3];
    oT[4]=(float)R10; oT[5]=(float)R11; oT[6]=(float)R12; oT[7]=(float)F[1][3];
    oT[8]=(float)R20; oT[9]=(float)R21; oT[10]=(float)R22; oT[11]=(float)F[2][3];
    oT[12]=0.f; oT[13]=0.f; oT[14]=0.f; oT[15]=1.f;
    double qw=0.5*sqrt(fmax(1e-12, 1.0+R00+R11+R22));
    double qx=0.5*sqrt(fmax(0.0, 1.0+R00-R11-R22));
    double qy=0.5*sqrt(fmax(0.0, 1.0-R00+R11-R22));
    double qz=0.5*sqrt(fmax(0.0, 1.0-R00-R11+R22));
    if (R21-R12<0.0) qx=-qx;
    if (R02-R20<0.0) qy=-qy;
    if (R10-R01<0.0) qz=-qz;
    float* oQ = out + 128 + b*4;
    oQ[0]=(float)qw; oQ[1]=(float)qx; oQ[2]=(float)qy; oQ[3]=(float)qz;
    float* ot3 = out + 160 + b*3;
    ot3[0]=(float)F[0][3]; ot3[1]=(float)F[1][3]; ot3[2]=(float)F[2][3];
  }
}

extern "C" void kernel_launch(void* const* d_in, const int* in_sizes, int n_in,
                              void* d_out, int out_size, void* d_ws, size_t ws_size,
                              hipStream_t stream) {
  const float* pc1 = (const float*)d_in[0];
  const float* pc2 = (const float*)d_in[1];
  float* out  = (float*)d_out;
  float* ws   = (float*)d_ws;
  float4* pack = (float4*)(ws + OFF_PACK);
  float* part  = ws + OFF_PART;
  float* pcn   = ws + OFF_PCN;
  float* dist  = ws + OFF_DIST;
  float* stats = ws + OFF_STATS;
  float* asums = ws + OFF_ASUM;

  hipLaunchKernelGGL(k_pack,  dim3(128), dim3(256), 0, stream, pc2, pack);
  hipLaunchKernelGGL(k_soft,  dim3(512), dim3(256), 0, stream, pc1, pack, part);
  hipLaunchKernelGGL(k_merge, dim3(8),   dim3(256), 0, stream, pc1, part, pcn, dist, stats);
  hipLaunchKernelGGL(k_accum, dim3(8),   dim3(256), 0, stream, pc1, pcn, dist, stats, asums);
  hipLaunchKernelGGL(k_solve, dim3(8),   dim3(64),  0, stream, asums, stats, out);
}

// Round 2
// 326.540 us; speedup vs baseline: 1.2630x; 1.2630x over previous
//
#include <hip/hip_runtime.h>
#include <math.h>

#define NPTS 4096
#define EPSC 1e-5f
#define LOG2E 1.44269504088896340736f
#define F2C (2.0f*LOG2E)

#if __has_builtin(__builtin_amdgcn_exp2f)
#define FEXP2 __builtin_amdgcn_exp2f
#else
#define FEXP2(x) __expf((x)*0.6931471805599453f)
#endif

__global__ void __launch_bounds__(256) k_pack(const float* __restrict__ pc2,
                                              float4* __restrict__ pack){
  int idx = blockIdx.x*256 + threadIdx.x;           // 32768 threads
  int b = idx >> 12, m = idx & 4095;
  const float* p = pc2 + (size_t)b*4*NPTS + m;
  float x = p[0], y = p[NPTS], z = p[2*NPTS];
  pack[idx] = make_float4(x, y, z, x*x + y*y + z*z);
}

// one thread = one pc1 row; one block = (sample, 256-row block, CHN-col chunk)
template<int CHN>
__global__ void __launch_bounds__(256) k_soft(const float* __restrict__ pc1,
                                              const float4* __restrict__ pack,
                                              float* __restrict__ part){
  constexpr int NC = NPTS/CHN;
  int bid = blockIdx.x;                              // 16*8*NC blocks
  int chunk = bid & (NC-1), rb = (bid/NC) & 15, b = bid/(NC*16);
  int n = rb*256 + threadIdx.x;
  const float* p1 = pc1 + (size_t)b*4*NPTS + n;
  float x1 = p1[0], y1 = p1[NPTS], z1 = p1[2*NPTS];
  float q1 = x1*x1 + y1*y1 + z1*z1;
  const float4* cp = pack + b*NPTS + chunk*CHN;      // wave-uniform -> s_load
  // pass 1: min distance (max score)
  float dmin = 3.4e38f;
  #pragma unroll 8
  for (int m=0; m<CHN; ++m){
    float4 c = cp[m];
    float dot = fmaf(x1,c.x,fmaf(y1,c.y,z1*c.z));
    float d = fmaf(-2.f,dot,q1) + c.w;
    dmin = fminf(dmin, d);
  }
  // exp2 units: smax2 = FACT*log2e / clip(dmin)
  float smax2 = F2C * __builtin_amdgcn_rcpf(fmaxf(dmin, EPSC));
  // pass 2: exp2-sum + weighted value accumulation
  float L=0.f, Ax=0.f, Ay=0.f, Az=0.f;
  #pragma unroll 8
  for (int m=0; m<CHN; ++m){
    float4 c = cp[m];
    float dot = fmaf(x1,c.x,fmaf(y1,c.y,z1*c.z));
    float d = fmaf(-2.f,dot,q1) + c.w;
    float inv = __builtin_amdgcn_rcpf(fmaxf(d, EPSC));
    float pe = FEXP2(fmaf(F2C, inv, -smax2));
    L += pe;
    Ax = fmaf(pe,c.x,Ax); Ay = fmaf(pe,c.y,Ay); Az = fmaf(pe,c.z,Az);
  }
  float* pp = part + ((size_t)(b*NC + chunk)*5)*NPTS + n;
  pp[0]=smax2; pp[NPTS]=L; pp[2*NPTS]=Ax; pp[3*NPTS]=Ay; pp[4*NPTS]=Az;
}

// merge chunk partials -> pc_nearest + dist; per-block partial stats sums
template<int NC>
__global__ void __launch_bounds__(256) k_merge(const float* __restrict__ pc1,
                                               const float* __restrict__ part,
                                               float* __restrict__ pcn,
                                               float* __restrict__ dist,
                                               float* __restrict__ psum13){
  int b = blockIdx.x >> 4, rb = blockIdx.x & 15, t = threadIdx.x;   // 128 blocks
  int n = rb*256 + t;
  float sc[NC], Lc[NC], Axc[NC], Ayc[NC], Azc[NC];
  float S = -3.4e38f;
  #pragma unroll
  for (int c=0;c<NC;c++){
    const float* pp = part + ((size_t)(b*NC+c)*5)*NPTS + n;
    sc[c]=pp[0]; Lc[c]=pp[NPTS]; Axc[c]=pp[2*NPTS]; Ayc[c]=pp[3*NPTS]; Azc[c]=pp[4*NPTS];
    S = fmaxf(S, sc[c]);
  }
  float L=0.f, Ax=0.f, Ay=0.f, Az=0.f;
  #pragma unroll
  for (int c=0;c<NC;c++){
    float w = FEXP2(sc[c]-S);
    L=fmaf(w,Lc[c],L); Ax=fmaf(w,Axc[c],Ax); Ay=fmaf(w,Ayc[c],Ay); Az=fmaf(w,Azc[c],Az);
  }
  float inv = 1.f/L;
  float px=Ax*inv, py=Ay*inv, pz=Az*inv;
  const float* p1 = pc1 + (size_t)b*4*NPTS + n;
  float x1=p1[0], y1=p1[NPTS], z1=p1[2*NPTS];
  float dx=x1-px, dy=y1-py, dz=z1-pz;
  float dd=sqrtf(dx*dx+dy*dy+dz*dz);
  pcn[(size_t)(b*3+0)*NPTS+n]=px;
  pcn[(size_t)(b*3+1)*NPTS+n]=py;
  pcn[(size_t)(b*3+2)*NPTS+n]=pz;
  dist[(size_t)b*NPTS+n]=dd;
  float acc[13]={x1,y1,z1,x1*x1,y1*y1,z1*z1,px,py,pz,px*px,py*py,pz*pz,dd};
  __shared__ float red[4][13];
  int lane = t & 63, wv = t >> 6;
  #pragma unroll
  for (int k=0;k<13;k++){
    float v = acc[k];
    v += __shfl_xor(v,32); v += __shfl_xor(v,16); v += __shfl_xor(v,8);
    v += __shfl_xor(v,4);  v += __shfl_xor(v,2);  v += __shfl_xor(v,1);
    if (lane==0) red[wv][k]=v;
  }
  __syncthreads();
  if (t<13) psum13[(size_t)(blockIdx.x)*13 + t] = red[0][t]+red[1][t]+red[2][t]+red[3][t];
}

// stats from psum13 + accumulate 4 weighted aa^T blocks of A = M^T M (partials)
__global__ void __launch_bounds__(256) k_accum(const float* __restrict__ pc1,
                                               const float* __restrict__ pcn,
                                               const float* __restrict__ dist,
                                               const float* __restrict__ psum13,
                                               float* __restrict__ stats,
                                               float* __restrict__ psum40){
  int b = blockIdx.x >> 4, rb = blockIdx.x & 15, t = threadIdx.x;   // 128 blocks
  __shared__ float stot[13];
  __shared__ float sst[13];
  if (t<13){
    float s=0.f;
    for (int i=0;i<16;i++) s += psum13[(size_t)(b*16+i)*13 + t];
    stot[t]=s;
  }
  __syncthreads();
  if (t==0){
    const float Nf = 4096.f, Nm1 = 4095.f;
    float st[13];
    #pragma unroll
    for (int j=0;j<3;j++){
      float m  = stot[j]/Nf;
      float v  = (stot[3+j]-Nf*m*m)/Nm1;      // ddof=1
      st[j]=m; st[3+j]=sqrtf(fmaxf(v,0.f));
      float m2 = stot[6+j]/Nf;
      float v2 = (stot[9+j]-Nf*m2*m2)/Nm1;
      st[6+j]=m2; st[9+j]=sqrtf(fmaxf(v2,0.f));
    }
    st[12]=stot[12]/Nf;
    #pragma unroll
    for (int k=0;k<13;k++){ sst[k]=st[k]; if (rb==0) stats[b*16+k]=st[k]; }
  }
  __syncthreads();
  float i1x=1.f/sst[3], i1y=1.f/sst[4], i1z=1.f/sst[5];
  float t1x=-sst[0]/sst[3], t1y=-sst[1]/sst[4], t1z=-sst[2]/sst[5];
  float i2x=1.f/sst[9], i2y=1.f/sst[10], i2z=1.f/sst[11];
  float t2x=-sst[6]/sst[9], t2y=-sst[7]/sst[10], t2z=-sst[8]/sst[11];
  float meanD=sst[12];
  int n = rb*256 + t;
  const float* p1 = pc1 + (size_t)b*4*NPTS + n;
  float X1=fmaf(p1[0],i1x,t1x), Y1=fmaf(p1[NPTS],i1y,t1y), Z1=fmaf(p1[2*NPTS],i1z,t1z);
  float X2=fmaf(pcn[(size_t)(b*3+0)*NPTS+n],i2x,t2x);
  float Y2=fmaf(pcn[(size_t)(b*3+1)*NPTS+n],i2y,t2y);
  float Z2=fmaf(pcn[(size_t)(b*3+2)*NPTS+n],i2z,t2z);
  // sigmoid((dist-mean-EPS)*-1e10) > 0.5  <=>  (dist-mean)-EPS < 0
  float zthr = (dist[(size_t)b*NPTS+n] - meanD) - EPSC;
  float msk = (zthr < 0.f) ? 1.f : 0.f;
  float tz = msk*Z2;
  float wA = tz*Z2, wB = -tz*X2, wC = -tz*Y2;
  float wD = msk*fmaf(X2,X2,Y2*Y2);
  float acc[40];
  float ee[10]={X1*X1, X1*Y1, X1*Z1, X1, Y1*Y1, Y1*Z1, Y1, Z1*Z1, Z1, 1.f};
  #pragma unroll
  for (int j=0;j<10;j++){
    acc[j]    = wA*ee[j];
    acc[10+j] = wB*ee[j];
    acc[20+j] = wC*ee[j];
    acc[30+j] = wD*ee[j];
  }
  __shared__ float red[4][40];
  int lane=t&63, wv=t>>6;
  #pragma unroll
  for (int k=0;k<40;k++){
    float v=acc[k];
    v+=__shfl_xor(v,32); v+=__shfl_xor(v,16); v+=__shfl_xor(v,8);
    v+=__shfl_xor(v,4);  v+=__shfl_xor(v,2);  v+=__shfl_xor(v,1);
    if(lane==0) red[wv][k]=v;
  }
  __syncthreads();
  if (t<40) psum40[(size_t)blockIdx.x*40 + t] = red[0][t]+red[1][t]+red[2][t]+red[3][t];
}

__device__ __forceinline__ float elemA(const float* S, int i, int k){
  int bi=i>>2, bj=k>>2;
  int ii=i&3, jj=k&3;
  int lo = ii<jj?ii:jj, hi = ii<jj?jj:ii;
  int pe = 4*lo - ((lo*(lo-1))>>1) + (hi-lo);        // sym 4x4 -> 10 idx
  int w;
  if (bi==bj) w = (bi==2)?30:0;
  else {
    int blo = bi<bj?bi:bj, bhi = bi<bj?bj:bi;
    if (blo==0 && bhi==1) return 0.f;                // A01 block is zero
    w = (blo==0)?10:20;                              // (0,2)->wB, (1,2)->wC
  }
  return S[w+pe];
}

// per-sample: 12x12 Jacobi eigensolve (lane-parallel, wave-synchronous) + compose
__global__ void __launch_bounds__(64) k_solve(const float* __restrict__ psum40,
                                              const float* __restrict__ stats,
                                              float* __restrict__ out){
  int b=blockIdx.x, t=threadIdx.x;                   // 8 blocks x 1 wave
  __shared__ float SS[40];
  if (t<40){
    float s=0.f;
    for (int i=0;i<16;i++) s += psum40[(size_t)(b*16+i)*40 + t];
    SS[t]=s;
  }
  __syncthreads();
  __shared__ float A[12][13];
  __shared__ float V[12][13];
  if (t<12){
    #pragma unroll
    for (int i=0;i<12;i++){
      A[i][t]=elemA(SS,i,t);
      V[i][t]=(i==t)?1.f:0.f;
    }
  }
  __builtin_amdgcn_wave_barrier();
  bool act = (t<12);
  for (int sweep=0; sweep<12; ++sweep){
    for (int r=0; r<11; ++r){
      // round-robin tournament pairing (circle method), 6 disjoint pairs
      int partner;
      if (t==0) partner = 1+r;
      else {
        int i = (t-1-r)%11; if (i<0) i+=11;
        partner = (i==0)?0:(1+(11-i+r)%11);
      }
      int p = t<partner?t:partner, q = t<partner?partner:t;
      float c=1.f, s=0.f;
      if (act){
        float apq=A[p][q];
        if (apq!=0.f){
          float tau=(A[q][q]-A[p][p])/(2.f*apq);
          float tt=1.f/(fabsf(tau)+sqrtf(fmaf(tau,tau,1.f)));
          if (tau<0.f) tt=-tt;
          c=1.f/sqrtf(fmaf(tt,tt,1.f));
          s=tt*c;
        }
      }
      float sg = (t==q)?s:-s;
      float na[12], nv[12];
      if (act){
        #pragma unroll
        for (int i=0;i<12;i++){
          na[i]=fmaf(c,A[i][t],sg*A[i][partner]);    // A <- A*J (columns)
          nv[i]=fmaf(c,V[i][t],sg*V[i][partner]);    // V <- V*J
        }
      }
      __builtin_amdgcn_wave_barrier();
      if (act){
        #pragma unroll
        for (int i=0;i<12;i++){ A[i][t]=na[i]; V[i][t]=nv[i]; }
      }
      __builtin_amdgcn_wave_barrier();
      if (act){
        #pragma unroll
        for (int j=0;j<12;j++) na[j]=fmaf(c,A[t][j],sg*A[partner][j]); // Jt*(AJ) rows
      }
      __builtin_amdgcn_wave_barrier();
      if (act){
        #pragma unroll
        for (int j=0;j<12;j++) A[t][j]=na[j];
      }
      __builtin_amdgcn_wave_barrier();
    }
  }
  if (t==0){
    float best=A[0][0]; int kb=0;
    #pragma unroll
    for (int i=1;i<12;i++){ if (A[i][i]<best){best=A[i][i];kb=i;} }
    double pv[12];
    #pragma unroll
    for (int i=0;i<12;i++) pv[i]=(double)V[i][kb];
    if (pv[10]<0.0){
      #pragma unroll
      for (int i=0;i<12;i++) pv[i]=-pv[i];
    }
    double nrm = sqrt(pv[8]*pv[8]+pv[9]*pv[9]+pv[10]*pv[10]);
    #pragma unroll
    for (int i=0;i<12;i++) pv[i]/=nrm;
    const float* st = stats + b*16;
    double m1[3]={st[0],st[1],st[2]}, sd1[3]={st[3],st[4],st[5]};
    double m2[3]={st[6],st[7],st[8]}, sd2[3]={st[9],st[10],st[11]};
    double Td[3][4]={{pv[0],pv[1],pv[2],pv[3]},
                     {pv[4],pv[5],pv[6],pv[7]},
                     {pv[8],pv[9],pv[10],pv[11]}};
    double F[3][4];
    for (int i=0;i<3;i++){
      double b3 = Td[i][3];
      for (int j=0;j<3;j++){
        F[i][j] = sd2[i]*(Td[i][j]/sd1[j]);          // inv(T2) @ Tdlt @ T1
        b3 += Td[i][j]*(-m1[j]/sd1[j]);
      }
      F[i][3] = sd2[i]*b3 + m2[i];
    }
    // normalize rotation: z=norm(col2); x=norm(cross(col1,z)); y=cross(z,x)
    double zx=F[0][2],zy=F[1][2],zz2=F[2][2];
    double zn=sqrt(zx*zx+zy*zy+zz2*zz2);
    zx/=zn; zy/=zn; zz2/=zn;
    double yx=F[0][1],yy=F[1][1],yz=F[2][1];
    double xx=yy*zz2-yz*zy, xy=yz*zx-yx*zz2, xz=yx*zy-yy*zx;
    double xn=sqrt(xx*xx+xy*xy+xz*xz);
    xx/=xn; xy/=xn; xz/=xn;
    double y2x=zy*xz-zz2*xy, y2y=zz2*xx-zx*xz, y2z=zx*xy-zy*xx;
    double R00=xx,R01=y2x,R02=zx;
    double R10=xy,R11=y2y,R12=zy;
    double R20=xz,R21=y2z,R22=zz2;
    float* oT = out + b*16;
    oT[0]=(float)R00; oT[1]=(float)R01; oT[2]=(float)R02; oT[3]=(float)F[0][3];
    oT[4]=(float)R10; oT[5]=(float)R11; oT[6]=(float)R12; oT[7]=(float)F[1][3];
    oT[8]=(float)R20; oT[9]=(float)R21; oT[10]=(float)R22; oT[11]=(float)F[2][3];
    oT[12]=0.f; oT[13]=0.f; oT[14]=0.f; oT[15]=1.f;
    double qw=0.5*sqrt(fmax(1e-12, 1.0+R00+R11+R22));
    double qx=0.5*sqrt(fmax(0.0, 1.0+R00-R11-R22));
    double qy=0.5*sqrt(fmax(0.0, 1.0-R00+R11-R22));
    double qz=0.5*sqrt(fmax(0.0, 1.0-R00-R11+R22));
    if (R21-R12<0.0) qx=-qx;
    if (R02-R20<0.0) qy=-qy;
    if (R10-R01<0.0) qz=-qz;
    float* oQ = out + 128 + b*4;
    oQ[0]=(float)qw; oQ[1]=(float)qx; oQ[2]=(float)qy; oQ[3]=(float)qz;
    float* ot3 = out + 160 + b*3;
    ot3[0]=(float)F[0][3]; ot3[1]=(float)F[1][3]; ot3[2]=(float)F[2][3];
  }
}

extern "C" void kernel_launch(void* const* d_in, const int* in_sizes, int n_in,
                              void* d_out, int out_size, void* d_ws, size_t ws_size,
                              hipStream_t stream) {
  const float* pc1 = (const float*)d_in[0];
  const float* pc2 = (const float*)d_in[1];
  float* out  = (float*)d_out;
  float* ws   = (float*)d_ws;

  // choose 8-way column split if workspace allows (needs ~6.4 MB), else 4-way
  size_t need8 = (size_t)(131072 + 8*8*5*NPTS + 98304 + 32768 + 128 + 1664 + 5120) * 4;
  int NC = (ws_size >= need8) ? 8 : 4;

  float4* pack  = (float4*)ws;                       // 131072 floats
  float*  part  = ws + 131072;                       // 8*NC*5*4096 floats
  float*  pcn   = part + (size_t)8*NC*5*NPTS;        // 98304
  float*  dist  = pcn + 98304;                       // 32768
  float*  stats = dist + 32768;                      // 128
  float*  psum13= stats + 128;                       // 8*16*13 = 1664
  float*  psum40= psum13 + 1664;                     // 8*16*40 = 5120

  hipLaunchKernelGGL(k_pack, dim3(128), dim3(256), 0, stream, pc2, pack);
  if (NC == 8){
    hipLaunchKernelGGL(k_soft<512>,  dim3(1024), dim3(256), 0, stream, pc1, pack, part);
    hipLaunchKernelGGL(k_merge<8>,   dim3(128),  dim3(256), 0, stream, pc1, part, pcn, dist, psum13);
  } else {
    hipLaunchKernelGGL(k_soft<1024>, dim3(512),  dim3(256), 0, stream, pc1, pack, part);
    hipLaunchKernelGGL(k_merge<4>,   dim3(128),  dim3(256), 0, stream, pc1, part, pcn, dist, psum13);
  }
  hipLaunchKernelGGL(k_accum, dim3(128), dim3(256), 0, stream, pc1, pcn, dist, psum13, stats, psum40);
  hipLaunchKernelGGL(k_solve, dim3(8),   dim3(64),  0, stream, psum40, stats, out);
}

// Round 3
// 230.458 us; speedup vs baseline: 1.7896x; 1.4169x over previous
//
#include <hip/hip_runtime.h>
#include <math.h>

#define NPTS 4096
#define EPSC 1e-5f
#define F2C (2.0f*1.44269504088896340736f)

#if __has_builtin(__builtin_amdgcn_exp2f)
#define FEXP2 __builtin_amdgcn_exp2f
#else
#define FEXP2(x) __expf((x)*0.6931471805599453f)
#endif

// one thread = one pc1 row; one block = (sample, 256-row block, CHN-col chunk)
// pc2 chunk staged in LDS (x,y,z,|p|^2) -> broadcast ds_read in inner loop.
template<int CHN>
__global__ void __launch_bounds__(256) k_soft(const float* __restrict__ pc1,
                                              const float* __restrict__ pc2,
                                              float* __restrict__ part){
  constexpr int NC = NPTS/CHN;
  int bid = blockIdx.x;
  int chunk = bid & (NC-1), rb = (bid/NC) & 15, b = bid/(NC*16);

  __shared__ float4 sp[CHN];                     // 4KB (CHN=256) / 8KB (512)
  {
    const float* p2 = pc2 + (size_t)b*4*NPTS + chunk*CHN;
    for (int m = threadIdx.x; m < CHN; m += 256){
      float x = p2[m], y = p2[m+NPTS], z = p2[m+2*NPTS];
      sp[m] = make_float4(x, y, z, x*x + y*y + z*z);
    }
  }
  __syncthreads();

  int n = rb*256 + threadIdx.x;
  const float* p1 = pc1 + (size_t)b*4*NPTS + n;
  float x1 = p1[0], y1 = p1[NPTS], z1 = p1[2*NPTS];
  float q1 = x1*x1 + y1*y1 + z1*z1;
  float mx = -2.f*x1, my = -2.f*y1, mz = -2.f*z1;

  // pass 1: min of u = |p2|^2 - 2<p1,p2>   (d = q1 + u)
  float umin = 3.4e38f;
  #pragma unroll 8
  for (int m=0; m<CHN; ++m){
    float4 c = sp[m];
    float u = fmaf(mx,c.x, fmaf(my,c.y, fmaf(mz,c.z, c.w)));
    umin = fminf(umin, u);
  }
  float smax2 = F2C * __builtin_amdgcn_rcpf(fmaxf(q1+umin, EPSC));

  // pass 2: exp2-sum + weighted value accumulation
  float L=0.f, Ax=0.f, Ay=0.f, Az=0.f;
  #pragma unroll 8
  for (int m=0; m<CHN; ++m){
    float4 c = sp[m];
    float u = fmaf(mx,c.x, fmaf(my,c.y, fmaf(mz,c.z, c.w)));
    float dinv = __builtin_amdgcn_rcpf(fmaxf(q1+u, EPSC));
    float pe = FEXP2(fmaf(F2C, dinv, -smax2));
    L += pe;
    Ax = fmaf(pe,c.x,Ax); Ay = fmaf(pe,c.y,Ay); Az = fmaf(pe,c.z,Az);
  }
  float* pp = part + ((size_t)(b*NC + chunk)*5)*NPTS + n;
  pp[0]=smax2; pp[NPTS]=L; pp[2*NPTS]=Ax; pp[3*NPTS]=Ay; pp[4*NPTS]=Az;
}

// merge chunk partials -> pc_nearest + dist; per-block partial stats sums.
// 512 threads: two 256-thread halves each merge NC/2 chunks, combine via LDS.
template<int NC>
__global__ void __launch_bounds__(512) k_merge(const float* __restrict__ pc1,
                                               const float* __restrict__ part,
                                               float* __restrict__ pcn,
                                               float* __restrict__ dist,
                                               float* __restrict__ psum13){
  int b = blockIdx.x >> 4, rb = blockIdx.x & 15;                    // 128 blocks
  int t = threadIdx.x & 255, half = threadIdx.x >> 8;
  int n = rb*256 + t;
  constexpr int H = NC/2;
  float sc[H], Lc[H], Axc[H], Ayc[H], Azc[H];
  float S = -3.4e38f;
  #pragma unroll
  for (int c=0;c<H;c++){
    const float* pp = part + ((size_t)(b*NC + half*H + c)*5)*NPTS + n;
    sc[c]=pp[0]; Lc[c]=pp[NPTS]; Axc[c]=pp[2*NPTS]; Ayc[c]=pp[3*NPTS]; Azc[c]=pp[4*NPTS];
    S = fmaxf(S, sc[c]);
  }
  float L=0.f, Ax=0.f, Ay=0.f, Az=0.f;
  #pragma unroll
  for (int c=0;c<H;c++){
    float w = FEXP2(sc[c]-S);
    L=fmaf(w,Lc[c],L); Ax=fmaf(w,Axc[c],Ax); Ay=fmaf(w,Ayc[c],Ay); Az=fmaf(w,Azc[c],Az);
  }
  __shared__ float ex[256][5];
  if (half==1){ ex[t][0]=S; ex[t][1]=L; ex[t][2]=Ax; ex[t][3]=Ay; ex[t][4]=Az; }
  __syncthreads();
  __shared__ float red[4][13];
  if (half==0){
    float S1=ex[t][0];
    float M = fmaxf(S,S1);
    float w0=FEXP2(S-M), w1=FEXP2(S1-M);
    L = w0*L + w1*ex[t][1];
    Ax = w0*Ax + w1*ex[t][2];
    Ay = w0*Ay + w1*ex[t][3];
    Az = w0*Az + w1*ex[t][4];
    float inv = 1.f/L;
    float px=Ax*inv, py=Ay*inv, pz=Az*inv;
    const float* p1 = pc1 + (size_t)b*4*NPTS + n;
    float x1=p1[0], y1=p1[NPTS], z1=p1[2*NPTS];
    float dx=x1-px, dy=y1-py, dz=z1-pz;
    float dd=sqrtf(dx*dx+dy*dy+dz*dz);
    pcn[(size_t)(b*3+0)*NPTS+n]=px;
    pcn[(size_t)(b*3+1)*NPTS+n]=py;
    pcn[(size_t)(b*3+2)*NPTS+n]=pz;
    dist[(size_t)b*NPTS+n]=dd;
    float acc[13]={x1,y1,z1,x1*x1,y1*y1,z1*z1,px,py,pz,px*px,py*py,pz*pz,dd};
    int lane = t & 63, wv = t >> 6;
    #pragma unroll
    for (int k=0;k<13;k++){
      float v = acc[k];
      v += __shfl_xor(v,32); v += __shfl_xor(v,16); v += __shfl_xor(v,8);
      v += __shfl_xor(v,4);  v += __shfl_xor(v,2);  v += __shfl_xor(v,1);
      if (lane==0) red[wv][k]=v;
    }
  }
  __syncthreads();
  if (threadIdx.x<13)
    psum13[(size_t)blockIdx.x*13 + threadIdx.x] =
      red[0][threadIdx.x]+red[1][threadIdx.x]+red[2][threadIdx.x]+red[3][threadIdx.x];
}

// stats from psum13 + accumulate 4 weighted aa^T blocks of A = M^T M (partials)
__global__ void __launch_bounds__(256) k_accum(const float* __restrict__ pc1,
                                               const float* __restrict__ pcn,
                                               const float* __restrict__ dist,
                                               const float* __restrict__ psum13,
                                               float* __restrict__ stats,
                                               float* __restrict__ psum40){
  int b = blockIdx.x >> 4, rb = blockIdx.x & 15, t = threadIdx.x;   // 128 blocks
  __shared__ float stot[13];
  __shared__ float sst[13];
  if (t<13){
    float s=0.f;
    #pragma unroll
    for (int i=0;i<16;i++) s += psum13[(size_t)(b*16+i)*13 + t];
    stot[t]=s;
  }
  __syncthreads();
  if (t==0){
    const float Nf = 4096.f, Nm1 = 4095.f;
    float st[13];
    #pragma unroll
    for (int j=0;j<3;j++){
      float m  = stot[j]/Nf;
      float v  = (stot[3+j]-Nf*m*m)/Nm1;      // ddof=1
      st[j]=m; st[3+j]=sqrtf(fmaxf(v,0.f));
      float m2 = stot[6+j]/Nf;
      float v2 = (stot[9+j]-Nf*m2*m2)/Nm1;
      st[6+j]=m2; st[9+j]=sqrtf(fmaxf(v2,0.f));
    }
    st[12]=stot[12]/Nf;
    #pragma unroll
    for (int k=0;k<13;k++){ sst[k]=st[k]; if (rb==0) stats[b*16+k]=st[k]; }
  }
  __syncthreads();
  float i1x=1.f/sst[3], i1y=1.f/sst[4], i1z=1.f/sst[5];
  float t1x=-sst[0]/sst[3], t1y=-sst[1]/sst[4], t1z=-sst[2]/sst[5];
  float i2x=1.f/sst[9], i2y=1.f/sst[10], i2z=1.f/sst[11];
  float t2x=-sst[6]/sst[9], t2y=-sst[7]/sst[10], t2z=-sst[8]/sst[11];
  float meanD=sst[12];
  int n = rb*256 + t;
  const float* p1 = pc1 + (size_t)b*4*NPTS + n;
  float X1=fmaf(p1[0],i1x,t1x), Y1=fmaf(p1[NPTS],i1y,t1y), Z1=fmaf(p1[2*NPTS],i1z,t1z);
  float X2=fmaf(pcn[(size_t)(b*3+0)*NPTS+n],i2x,t2x);
  float Y2=fmaf(pcn[(size_t)(b*3+1)*NPTS+n],i2y,t2y);
  float Z2=fmaf(pcn[(size_t)(b*3+2)*NPTS+n],i2z,t2z);
  float zthr = (dist[(size_t)b*NPTS+n] - meanD) - EPSC;
  float msk = (zthr < 0.f) ? 1.f : 0.f;
  float tz = msk*Z2;
  float wA = tz*Z2, wB = -tz*X2, wC = -tz*Y2;
  float wD = msk*fmaf(X2,X2,Y2*Y2);
  float acc[40];
  float ee[10]={X1*X1, X1*Y1, X1*Z1, X1, Y1*Y1, Y1*Z1, Y1, Z1*Z1, Z1, 1.f};
  #pragma unroll
  for (int j=0;j<10;j++){
    acc[j]    = wA*ee[j];
    acc[10+j] = wB*ee[j];
    acc[20+j] = wC*ee[j];
    acc[30+j] = wD*ee[j];
  }
  __shared__ float red[4][40];
  int lane=t&63, wv=t>>6;
  #pragma unroll
  for (int k=0;k<40;k++){
    float v=acc[k];
    v+=__shfl_xor(v,32); v+=__shfl_xor(v,16); v+=__shfl_xor(v,8);
    v+=__shfl_xor(v,4);  v+=__shfl_xor(v,2);  v+=__shfl_xor(v,1);
    if(lane==0) red[wv][k]=v;
  }
  __syncthreads();
  if (t<40) psum40[(size_t)blockIdx.x*40 + t] = red[0][t]+red[1][t]+red[2][t]+red[3][t];
}

__device__ __forceinline__ float elemA(const float* S, int i, int k){
  int bi=i>>2, bj=k>>2;
  int ii=i&3, jj=k&3;
  int lo = ii<jj?ii:jj, hi = ii<jj?jj:ii;
  int pe = 4*lo - ((lo*(lo-1))>>1) + (hi-lo);        // sym 4x4 -> 10 idx
  int w;
  if (bi==bj) w = (bi==2)?30:0;
  else {
    int blo = bi<bj?bi:bj, bhi = bi<bj?bj:bi;
    if (blo==0 && bhi==1) return 0.f;                // A01 block is zero
    w = (blo==0)?10:20;                              // (0,2)->wB, (1,2)->wC
  }
  return S[w+pe];
}

// per-sample: 12x12 Jacobi eigensolve (7 sweeps) + compose
__global__ void __launch_bounds__(64) k_solve(const float* __restrict__ psum40,
                                              const float* __restrict__ stats,
                                              float* __restrict__ out){
  int b=blockIdx.x, t=threadIdx.x;                   // 8 blocks x 1 wave
  __shared__ float SS[40];
  if (t<40){
    float s=0.f;
    #pragma unroll
    for (int i=0;i<16;i++) s += psum40[(size_t)(b*16+i)*40 + t];
    SS[t]=s;
  }
  __syncthreads();
  __shared__ float A[12][13];
  __shared__ float V[12][13];
  if (t<12){
    #pragma unroll
    for (int i=0;i<12;i++){
      A[i][t]=elemA(SS,i,t);
      V[i][t]=(i==t)?1.f:0.f;
    }
  }
  __builtin_amdgcn_wave_barrier();
  bool act = (t<12);
  for (int sweep=0; sweep<7; ++sweep){
    for (int r=0; r<11; ++r){
      int partner;
      if (t==0) partner = 1+r;
      else {
        int i = (t-1-r)%11; if (i<0) i+=11;
        partner = (i==0)?0:(1+(11-i+r)%11);
      }
      int p = t<partner?t:partner, q = t<partner?partner:t;
      float c=1.f, s=0.f;
      if (act){
        float apq=A[p][q];
        if (apq!=0.f){
          float tau=(A[q][q]-A[p][p])/(2.f*apq);
          float tt=1.f/(fabsf(tau)+sqrtf(fmaf(tau,tau,1.f)));
          if (tau<0.f) tt=-tt;
          c=1.f/sqrtf(fmaf(tt,tt,1.f));
          s=tt*c;
        }
      }
      float sg = (t==q)?s:-s;
      float na[12], nv[12];
      if (act){
        #pragma unroll
        for (int i=0;i<12;i++){
          na[i]=fmaf(c,A[i][t],sg*A[i][partner]);
          nv[i]=fmaf(c,V[i][t],sg*V[i][partner]);
        }
      }
      __builtin_amdgcn_wave_barrier();
      if (act){
        #pragma unroll
        for (int i=0;i<12;i++){ A[i][t]=na[i]; V[i][t]=nv[i]; }
      }
      __builtin_amdgcn_wave_barrier();
      if (act){
        #pragma unroll
        for (int j=0;j<12;j++) na[j]=fmaf(c,A[t][j],sg*A[partner][j]);
      }
      __builtin_amdgcn_wave_barrier();
      if (act){
        #pragma unroll
        for (int j=0;j<12;j++) A[t][j]=na[j];
      }
      __builtin_amdgcn_wave_barrier();
    }
  }
  if (t==0){
    float best=A[0][0]; int kb=0;
    #pragma unroll
    for (int i=1;i<12;i++){ if (A[i][i]<best){best=A[i][i];kb=i;} }
    double pv[12];
    #pragma unroll
    for (int i=0;i<12;i++) pv[i]=(double)V[i][kb];
    if (pv[10]<0.0){
      #pragma unroll
      for (int i=0;i<12;i++) pv[i]=-pv[i];
    }
    double nrm = sqrt(pv[8]*pv[8]+pv[9]*pv[9]+pv[10]*pv[10]);
    #pragma unroll
    for (int i=0;i<12;i++) pv[i]/=nrm;
    const float* st = stats + b*16;
    double m1[3]={st[0],st[1],st[2]}, sd1[3]={st[3],st[4],st[5]};
    double m2[3]={st[6],st[7],st[8]}, sd2[3]={st[9],st[10],st[11]};
    double Td[3][4]={{pv[0],pv[1],pv[2],pv[3]},
                     {pv[4],pv[5],pv[6],pv[7]},
                     {pv[8],pv[9],pv[10],pv[11]}};
    double F[3][4];
    for (int i=0;i<3;i++){
      double b3 = Td[i][3];
      for (int j=0;j<3;j++){
        F[i][j] = sd2[i]*(Td[i][j]/sd1[j]);
        b3 += Td[i][j]*(-m1[j]/sd1[j]);
      }
      F[i][3] = sd2[i]*b3 + m2[i];
    }
    double zx=F[0][2],zy=F[1][2],zz2=F[2][2];
    double zn=sqrt(zx*zx+zy*zy+zz2*zz2);
    zx/=zn; zy/=zn; zz2/=zn;
    double yx=F[0][1],yy=F[1][1],yz=F[2][1];
    double xx=yy*zz2-yz*zy, xy=yz*zx-yx*zz2, xz=yx*zy-yy*zx;
    double xn=sqrt(xx*xx+xy*xy+xz*xz);
    xx/=xn; xy/=xn; xz/=xn;
    double y2x=zy*xz-zz2*xy, y2y=zz2*xx-zx*xz, y2z=zx*xy-zy*xx;
    double R00=xx,R01=y2x,R02=zx;
    double R10=xy,R11=y2y,R12=zy;
    double R20=xz,R21=y2z,R22=zz2;
    float* oT = out + b*16;
    oT[0]=(float)R00; oT[1]=(float)R01; oT[2]=(float)R02; oT[3]=(float)F[0][3];
    oT[4]=(float)R10; oT[5]=(float)R11; oT[6]=(float)R12; oT[7]=(float)F[1][3];
    oT[8]=(float)R20; oT[9]=(float)R21; oT[10]=(float)R22; oT[11]=(float)F[2][3];
    oT[12]=0.f; oT[13]=0.f; oT[14]=0.f; oT[15]=1.f;
    double qw=0.5*sqrt(fmax(1e-12, 1.0+R00+R11+R22));
    double qx=0.5*sqrt(fmax(0.0, 1.0+R00-R11-R22));
    double qy=0.5*sqrt(fmax(0.0, 1.0-R00+R11-R22));
    double qz=0.5*sqrt(fmax(0.0, 1.0-R00-R11+R22));
    if (R21-R12<0.0) qx=-qx;
    if (R02-R20<0.0) qy=-qy;
    if (R10-R01<0.0) qz=-qz;
    float* oQ = out + 128 + b*4;
    oQ[0]=(float)qw; oQ[1]=(float)qx; oQ[2]=(float)qy; oQ[3]=(float)qz;
    float* ot3 = out + 160 + b*3;
    ot3[0]=(float)F[0][3]; ot3[1]=(float)F[1][3]; ot3[2]=(float)F[2][3];
  }
}

extern "C" void kernel_launch(void* const* d_in, const int* in_sizes, int n_in,
                              void* d_out, int out_size, void* d_ws, size_t ws_size,
                              hipStream_t stream) {
  const float* pc1 = (const float*)d_in[0];
  const float* pc2 = (const float*)d_in[1];
  float* out  = (float*)d_out;
  float* ws   = (float*)d_ws;

  // NC=16 (8 waves/SIMD) if ws allows (~11.1 MB), else NC=8 (~5.9 MB, proven fits)
  const size_t fixed = 98304 + 32768 + 128 + 128*13 + 128*40;
  size_t need16 = ((size_t)8*16*5*NPTS + fixed) * 4;
  int NC = (ws_size >= need16) ? 16 : 8;

  float* part  = ws;                                  // 8*NC*5*4096
  float* pcn   = part + (size_t)8*NC*5*NPTS;          // 98304
  float* dist  = pcn + 98304;                         // 32768
  float* stats = dist + 32768;                        // 128
  float* psum13= stats + 128;                         // 1664
  float* psum40= psum13 + 128*13;                     // 5120

  if (NC == 16){
    hipLaunchKernelGGL(k_soft<256>,  dim3(2048), dim3(256), 0, stream, pc1, pc2, part);
    hipLaunchKernelGGL(k_merge<16>,  dim3(128),  dim3(512), 0, stream, pc1, part, pcn, dist, psum13);
  } else {
    hipLaunchKernelGGL(k_soft<512>,  dim3(1024), dim3(256), 0, stream, pc1, pc2, part);
    hipLaunchKernelGGL(k_merge<8>,   dim3(128),  dim3(512), 0, stream, pc1, part, pcn, dist, psum13);
  }
  hipLaunchKernelGGL(k_accum, dim3(128), dim3(256), 0, stream, pc1, pcn, dist, psum13, stats, psum40);
  hipLaunchKernelGGL(k_solve, dim3(8),   dim3(64),  0, stream, psum40, stats, out);
}

// Round 4
// 221.604 us; speedup vs baseline: 1.8611x; 1.0400x over previous
//
#include <hip/hip_runtime.h>
#include <math.h>

#define NPTS 4096
#define EPSC 1e-5f
#define F2C (2.0f*1.44269504088896340736f)

#if __has_builtin(__builtin_amdgcn_exp2f)
#define FEXP2 __builtin_amdgcn_exp2f
#else
#define FEXP2(x) __expf((x)*0.6931471805599453f)
#endif

// one thread = one pc1 row; one block = (sample, 256-row block, CHN-col chunk)
// pc2 chunk staged in LDS; ONLINE softmax (single pass, deferred per-wave rescale).
template<int CHN>
__global__ void __launch_bounds__(256) k_soft(const float* __restrict__ pc1,
                                              const float* __restrict__ pc2,
                                              float* __restrict__ part){
  constexpr int NC = NPTS/CHN;
  int bid = blockIdx.x;
  int chunk = bid & (NC-1), rb = (bid/NC) & 15, b = bid/(NC*16);

  __shared__ float4 sp[CHN];                     // 4KB (CHN=256)
  {
    const float* p2 = pc2 + (size_t)b*4*NPTS + chunk*CHN;
    for (int m = threadIdx.x; m < CHN; m += 256){
      float x = p2[m], y = p2[m+NPTS], z = p2[m+2*NPTS];
      sp[m] = make_float4(x, y, z, x*x + y*y + z*z);
    }
  }
  __syncthreads();

  int n = rb*256 + threadIdx.x;
  const float* p1 = pc1 + (size_t)b*4*NPTS + n;
  float x1 = p1[0], y1 = p1[NPTS], z1 = p1[2*NPTS];
  float q1 = x1*x1 + y1*y1 + z1*z1;
  float mx = -2.f*x1, my = -2.f*y1, mz = -2.f*z1;

  // peel column 0: d = |p1-p2|^2 = q1 + |p2|^2 - 2<p1,p2>
  float4 c0 = sp[0];
  float d0 = fmaf(mx,c0.x, fmaf(my,c0.y, fmaf(mz,c0.z, c0.w + q1)));
  float m_ = F2C * __builtin_amdgcn_rcpf(fmaxf(d0, EPSC));   // running max (log2 units)
  float L = 1.f, Ax = c0.x, Ay = c0.y, Az = c0.z;

  #pragma unroll 8
  for (int mm=1; mm<CHN; ++mm){
    float4 c = sp[mm];
    float d = fmaf(mx,c.x, fmaf(my,c.y, fmaf(mz,c.z, c.w + q1)));
    float dinv = __builtin_amdgcn_rcpf(fmaxf(d, EPSC));
    float t = fmaf(F2C, dinv, -m_);              // s - m
    if (__any(t > 0.f)){                         // wave-uniform rescale (rare)
      float tp = fmaxf(t, 0.f);
      float sc = FEXP2(-tp);
      L *= sc; Ax *= sc; Ay *= sc; Az *= sc;
      m_ += tp;
      t = fminf(t, 0.f);                         // s - m_new
    }
    float pe = FEXP2(t);
    L += pe;
    Ax = fmaf(pe,c.x,Ax); Ay = fmaf(pe,c.y,Ay); Az = fmaf(pe,c.z,Az);
  }
  float* pp = part + ((size_t)(b*NC + chunk)*5)*NPTS + n;
  pp[0]=m_; pp[NPTS]=L; pp[2*NPTS]=Ax; pp[3*NPTS]=Ay; pp[4*NPTS]=Az;
}

// merge chunk partials -> pc_nearest + dist; per-block partial stats sums.
// 512 threads: two 256-thread halves each merge NC/2 chunks, combine via LDS.
template<int NC>
__global__ void __launch_bounds__(512) k_merge(const float* __restrict__ pc1,
                                               const float* __restrict__ part,
                                               float* __restrict__ pcn,
                                               float* __restrict__ dist,
                                               float* __restrict__ psum13){
  int b = blockIdx.x >> 4, rb = blockIdx.x & 15;                    // 128 blocks
  int t = threadIdx.x & 255, half = threadIdx.x >> 8;
  int n = rb*256 + t;
  constexpr int H = NC/2;
  float sc[H], Lc[H], Axc[H], Ayc[H], Azc[H];
  float S = -3.4e38f;
  #pragma unroll
  for (int c=0;c<H;c++){
    const float* pp = part + ((size_t)(b*NC + half*H + c)*5)*NPTS + n;
    sc[c]=pp[0]; Lc[c]=pp[NPTS]; Axc[c]=pp[2*NPTS]; Ayc[c]=pp[3*NPTS]; Azc[c]=pp[4*NPTS];
    S = fmaxf(S, sc[c]);
  }
  float L=0.f, Ax=0.f, Ay=0.f, Az=0.f;
  #pragma unroll
  for (int c=0;c<H;c++){
    float w = FEXP2(sc[c]-S);
    L=fmaf(w,Lc[c],L); Ax=fmaf(w,Axc[c],Ax); Ay=fmaf(w,Ayc[c],Ay); Az=fmaf(w,Azc[c],Az);
  }
  __shared__ float ex[256][5];
  if (half==1){ ex[t][0]=S; ex[t][1]=L; ex[t][2]=Ax; ex[t][3]=Ay; ex[t][4]=Az; }
  __syncthreads();
  __shared__ float red[4][13];
  if (half==0){
    float S1=ex[t][0];
    float M = fmaxf(S,S1);
    float w0=FEXP2(S-M), w1=FEXP2(S1-M);
    L = w0*L + w1*ex[t][1];
    Ax = w0*Ax + w1*ex[t][2];
    Ay = w0*Ay + w1*ex[t][3];
    Az = w0*Az + w1*ex[t][4];
    float inv = 1.f/L;
    float px=Ax*inv, py=Ay*inv, pz=Az*inv;
    const float* p1 = pc1 + (size_t)b*4*NPTS + n;
    float x1=p1[0], y1=p1[NPTS], z1=p1[2*NPTS];
    float dx=x1-px, dy=y1-py, dz=z1-pz;
    float dd=sqrtf(dx*dx+dy*dy+dz*dz);
    pcn[(size_t)(b*3+0)*NPTS+n]=px;
    pcn[(size_t)(b*3+1)*NPTS+n]=py;
    pcn[(size_t)(b*3+2)*NPTS+n]=pz;
    dist[(size_t)b*NPTS+n]=dd;
    float acc[13]={x1,y1,z1,x1*x1,y1*y1,z1*z1,px,py,pz,px*px,py*py,pz*pz,dd};
    int lane = t & 63, wv = t >> 6;
    #pragma unroll
    for (int k=0;k<13;k++){
      float v = acc[k];
      v += __shfl_xor(v,32); v += __shfl_xor(v,16); v += __shfl_xor(v,8);
      v += __shfl_xor(v,4);  v += __shfl_xor(v,2);  v += __shfl_xor(v,1);
      if (lane==0) red[wv][k]=v;
    }
  }
  __syncthreads();
  if (threadIdx.x<13)
    psum13[(size_t)blockIdx.x*13 + threadIdx.x] =
      red[0][threadIdx.x]+red[1][threadIdx.x]+red[2][threadIdx.x]+red[3][threadIdx.x];
}

__device__ __forceinline__ float elemA(const float* S, int i, int k){
  int bi=i>>2, bj=k>>2;
  int ii=i&3, jj=k&3;
  int lo = ii<jj?ii:jj, hi = ii<jj?jj:ii;
  int pe = 4*lo - ((lo*(lo-1))>>1) + (hi-lo);        // sym 4x4 -> 10 idx
  int w;
  if (bi==bj) w = (bi==2)?30:0;
  else {
    int blo = bi<bj?bi:bj, bhi = bi<bj?bj:bi;
    if (blo==0 && bhi==1) return 0.f;                // A01 block is zero
    w = (blo==0)?10:20;                              // (0,2)->wB, (1,2)->wC
  }
  return S[w+pe];
}

// fused per-sample: stats -> M^T M accumulation -> 12x12 Jacobi (wave 0) -> compose
__global__ void __launch_bounds__(256) k_solve(const float* __restrict__ pc1,
                                               const float* __restrict__ pcn,
                                               const float* __restrict__ dist,
                                               const float* __restrict__ psum13,
                                               float* __restrict__ out){
  int b=blockIdx.x, t=threadIdx.x;                   // 8 blocks x 4 waves
  __shared__ float stot[13];
  __shared__ float sst[13];
  if (t<13){
    float s=0.f;
    #pragma unroll
    for (int i=0;i<16;i++) s += psum13[(size_t)(b*16+i)*13 + t];
    stot[t]=s;
  }
  __syncthreads();
  if (t==0){
    const float Nf = 4096.f, Nm1 = 4095.f;
    #pragma unroll
    for (int j=0;j<3;j++){
      float m  = stot[j]/Nf;
      float v  = (stot[3+j]-Nf*m*m)/Nm1;             // ddof=1
      sst[j]=m; sst[3+j]=sqrtf(fmaxf(v,0.f));
      float m2 = stot[6+j]/Nf;
      float v2 = (stot[9+j]-Nf*m2*m2)/Nm1;
      sst[6+j]=m2; sst[9+j]=sqrtf(fmaxf(v2,0.f));
    }
    sst[12]=stot[12]/Nf;
  }
  __syncthreads();
  float i1x=1.f/sst[3], i1y=1.f/sst[4], i1z=1.f/sst[5];
  float t1x=-sst[0]/sst[3], t1y=-sst[1]/sst[4], t1z=-sst[2]/sst[5];
  float i2x=1.f/sst[9], i2y=1.f/sst[10], i2z=1.f/sst[11];
  float t2x=-sst[6]/sst[9], t2y=-sst[7]/sst[10], t2z=-sst[8]/sst[11];
  float meanD=sst[12];

  float acc[40];
  #pragma unroll
  for (int k=0;k<40;k++) acc[k]=0.f;
  for (int i=0;i<16;i++){
    int n=i*256+t;
    const float* p1 = pc1 + (size_t)b*4*NPTS + n;
    float X1=fmaf(p1[0],i1x,t1x), Y1=fmaf(p1[NPTS],i1y,t1y), Z1=fmaf(p1[2*NPTS],i1z,t1z);
    float X2=fmaf(pcn[(size_t)(b*3+0)*NPTS+n],i2x,t2x);
    float Y2=fmaf(pcn[(size_t)(b*3+1)*NPTS+n],i2y,t2y);
    float Z2=fmaf(pcn[(size_t)(b*3+2)*NPTS+n],i2z,t2z);
    // sigmoid((dist-mean-EPS)*-1e10) > 0.5  <=>  (dist-mean)-EPS < 0
    float zthr = (dist[(size_t)b*NPTS+n] - meanD) - EPSC;
    float msk = (zthr < 0.f) ? 1.f : 0.f;
    float tz = msk*Z2;
    float wA = tz*Z2, wB = -tz*X2, wC = -tz*Y2;
    float wD = msk*fmaf(X2,X2,Y2*Y2);
    float ee[10]={X1*X1, X1*Y1, X1*Z1, X1, Y1*Y1, Y1*Z1, Y1, Z1*Z1, Z1, 1.f};
    #pragma unroll
    for (int j=0;j<10;j++){
      acc[j]    = fmaf(wA,ee[j],acc[j]);
      acc[10+j] = fmaf(wB,ee[j],acc[10+j]);
      acc[20+j] = fmaf(wC,ee[j],acc[20+j]);
      acc[30+j] = fmaf(wD,ee[j],acc[30+j]);
    }
  }
  __shared__ float red[4][40];
  __shared__ float SS[40];
  {
    int lane=t&63, wv=t>>6;
    #pragma unroll
    for (int k=0;k<40;k++){
      float v=acc[k];
      v+=__shfl_xor(v,32); v+=__shfl_xor(v,16); v+=__shfl_xor(v,8);
      v+=__shfl_xor(v,4);  v+=__shfl_xor(v,2);  v+=__shfl_xor(v,1);
      if(lane==0) red[wv][k]=v;
    }
  }
  __syncthreads();
  if (t<40) SS[t]=red[0][t]+red[1][t]+red[2][t]+red[3][t];
  __syncthreads();

  if (t<64){                                        // Jacobi on wave 0 only
    __shared__ float A[12][13];
    __shared__ float V[12][13];
    if (t<12){
      #pragma unroll
      for (int i=0;i<12;i++){
        A[i][t]=elemA(SS,i,t);
        V[i][t]=(i==t)?1.f:0.f;
      }
    }
    __builtin_amdgcn_wave_barrier();
    bool act = (t<12);
    for (int sweep=0; sweep<7; ++sweep){
      for (int r=0; r<11; ++r){
        int partner;
        if (t==0) partner = 1+r;
        else {
          int i = (t-1-r)%11; if (i<0) i+=11;
          partner = (i==0)?0:(1+(11-i+r)%11);
        }
        int p = t<partner?t:partner, q = t<partner?partner:t;
        float c=1.f, s=0.f;
        if (act){
          float apq=A[p][q];
          if (apq!=0.f){
            float tau=(A[q][q]-A[p][p])/(2.f*apq);
            float tt=1.f/(fabsf(tau)+sqrtf(fmaf(tau,tau,1.f)));
            if (tau<0.f) tt=-tt;
            c=1.f/sqrtf(fmaf(tt,tt,1.f));
            s=tt*c;
          }
        }
        float sg = (t==q)?s:-s;
        float na[12], nv[12];
        if (act){
          #pragma unroll
          for (int i=0;i<12;i++){
            na[i]=fmaf(c,A[i][t],sg*A[i][partner]);
            nv[i]=fmaf(c,V[i][t],sg*V[i][partner]);
          }
        }
        __builtin_amdgcn_wave_barrier();
        if (act){
          #pragma unroll
          for (int i=0;i<12;i++){ A[i][t]=na[i]; V[i][t]=nv[i]; }
        }
        __builtin_amdgcn_wave_barrier();
        if (act){
          #pragma unroll
          for (int j=0;j<12;j++) na[j]=fmaf(c,A[t][j],sg*A[partner][j]);
        }
        __builtin_amdgcn_wave_barrier();
        if (act){
          #pragma unroll
          for (int j=0;j<12;j++) A[t][j]=na[j];
        }
        __builtin_amdgcn_wave_barrier();
      }
    }
    if (t==0){
      float best=A[0][0]; int kb=0;
      #pragma unroll
      for (int i=1;i<12;i++){ if (A[i][i]<best){best=A[i][i];kb=i;} }
      double pv[12];
      #pragma unroll
      for (int i=0;i<12;i++) pv[i]=(double)V[i][kb];
      if (pv[10]<0.0){
        #pragma unroll
        for (int i=0;i<12;i++) pv[i]=-pv[i];
      }
      double nrm = sqrt(pv[8]*pv[8]+pv[9]*pv[9]+pv[10]*pv[10]);
      #pragma unroll
      for (int i=0;i<12;i++) pv[i]/=nrm;
      double m1[3]={sst[0],sst[1],sst[2]}, sd1[3]={sst[3],sst[4],sst[5]};
      double m2[3]={sst[6],sst[7],sst[8]}, sd2[3]={sst[9],sst[10],sst[11]};
      double Td[3][4]={{pv[0],pv[1],pv[2],pv[3]},
                       {pv[4],pv[5],pv[6],pv[7]},
                       {pv[8],pv[9],pv[10],pv[11]}};
      double F[3][4];
      for (int i=0;i<3;i++){
        double b3 = Td[i][3];
        for (int j=0;j<3;j++){
          F[i][j] = sd2[i]*(Td[i][j]/sd1[j]);        // inv(T2) @ Tdlt @ T1
          b3 += Td[i][j]*(-m1[j]/sd1[j]);
        }
        F[i][3] = sd2[i]*b3 + m2[i];
      }
      double zx=F[0][2],zy=F[1][2],zz2=F[2][2];
      double zn=sqrt(zx*zx+zy*zy+zz2*zz2);
      zx/=zn; zy/=zn; zz2/=zn;
      double yx=F[0][1],yy=F[1][1],yz=F[2][1];
      double xx=yy*zz2-yz*zy, xy=yz*zx-yx*zz2, xz=yx*zy-yy*zx;
      double xn=sqrt(xx*xx+xy*xy+xz*xz);
      xx/=xn; xy/=xn; xz/=xn;
      double y2x=zy*xz-zz2*xy, y2y=zz2*xx-zx*xz, y2z=zx*xy-zy*xx;
      double R00=xx,R01=y2x,R02=zx;
      double R10=xy,R11=y2y,R12=zy;
      double R20=xz,R21=y2z,R22=zz2;
      float* oT = out + b*16;
      oT[0]=(float)R00; oT[1]=(float)R01; oT[2]=(float)R02; oT[3]=(float)F[0][3];
      oT[4]=(float)R10; oT[5]=(float)R11; oT[6]=(float)R12; oT[7]=(float)F[1][3];
      oT[8]=(float)R20; oT[9]=(float)R21; oT[10]=(float)R22; oT[11]=(float)F[2][3];
      oT[12]=0.f; oT[13]=0.f; oT[14]=0.f; oT[15]=1.f;
      double qw=0.5*sqrt(fmax(1e-12, 1.0+R00+R11+R22));
      double qx=0.5*sqrt(fmax(0.0, 1.0+R00-R11-R22));
      double qy=0.5*sqrt(fmax(0.0, 1.0-R00+R11-R22));
      double qz=0.5*sqrt(fmax(0.0, 1.0-R00-R11+R22));
      if (R21-R12<0.0) qx=-qx;
      if (R02-R20<0.0) qy=-qy;
      if (R10-R01<0.0) qz=-qz;
      float* oQ = out + 128 + b*4;
      oQ[0]=(float)qw; oQ[1]=(float)qx; oQ[2]=(float)qy; oQ[3]=(float)qz;
      float* ot3 = out + 160 + b*3;
      ot3[0]=(float)F[0][3]; ot3[1]=(float)F[1][3]; ot3[2]=(float)F[2][3];
    }
  }
}

extern "C" void kernel_launch(void* const* d_in, const int* in_sizes, int n_in,
                              void* d_out, int out_size, void* d_ws, size_t ws_size,
                              hipStream_t stream) {
  const float* pc1 = (const float*)d_in[0];
  const float* pc2 = (const float*)d_in[1];
  float* out  = (float*)d_out;
  float* ws   = (float*)d_ws;

  // NC=16 (2048 blocks) if ws allows (~11 MB), else NC=8
  const size_t fixed = 98304 + 32768 + 128*13;
  size_t need16 = ((size_t)8*16*5*NPTS + fixed) * 4;
  int NC = (ws_size >= need16) ? 16 : 8;

  float* part  = ws;                                  // 8*NC*5*4096
  float* pcn   = part + (size_t)8*NC*5*NPTS;          // 98304
  float* dist  = pcn + 98304;                         // 32768
  float* psum13= dist + 32768;                        // 1664

  if (NC == 16){
    hipLaunchKernelGGL(k_soft<256>,  dim3(2048), dim3(256), 0, stream, pc1, pc2, part);
    hipLaunchKernelGGL(k_merge<16>,  dim3(128),  dim3(512), 0, stream, pc1, part, pcn, dist, psum13);
  } else {
    hipLaunchKernelGGL(k_soft<512>,  dim3(1024), dim3(256), 0, stream, pc1, pc2, part);
    hipLaunchKernelGGL(k_merge<8>,   dim3(128),  dim3(512), 0, stream, pc1, part, pcn, dist, psum13);
  }
  hipLaunchKernelGGL(k_solve, dim3(8), dim3(256), 0, stream, pc1, pcn, dist, psum13, out);
}

// Round 6
// 156.875 us; speedup vs baseline: 2.6291x; 1.4126x over previous
//
#include <hip/hip_runtime.h>
#include <math.h>

#define NPTS 4096
#define EPSC 1e-5f
#define F2C (2.0f*1.44269504088896340736f)

#if __has_builtin(__builtin_amdgcn_exp2f)
#define FEXP2 __builtin_amdgcn_exp2f
#else
#define FEXP2(x) __expf((x)*0.6931471805599453f)
#endif

#define IDX(i,j) ((i)*((i)+1)/2 + (j))   // packed lower-tri, i>=j

// one thread = one pc1 row; one block = (sample, 256-row block, CHN-col chunk)
// pc2 chunk staged in LDS; ONLINE softmax (single pass, deferred per-wave rescale).
template<int CHN>
__global__ void __launch_bounds__(256) k_soft(const float* __restrict__ pc1,
                                              const float* __restrict__ pc2,
                                              float* __restrict__ part){
  constexpr int NC = NPTS/CHN;
  int bid = blockIdx.x;
  int chunk = bid & (NC-1), rb = (bid/NC) & 15, b = bid/(NC*16);

  __shared__ float4 sp[CHN];                     // 4KB (CHN=256)
  {
    const float* p2 = pc2 + (size_t)b*4*NPTS + chunk*CHN;
    for (int m = threadIdx.x; m < CHN; m += 256){
      float x = p2[m], y = p2[m+NPTS], z = p2[m+2*NPTS];
      sp[m] = make_float4(x, y, z, x*x + y*y + z*z);
    }
  }
  __syncthreads();

  int n = rb*256 + threadIdx.x;
  const float* p1 = pc1 + (size_t)b*4*NPTS + n;
  float x1 = p1[0], y1 = p1[NPTS], z1 = p1[2*NPTS];
  float q1 = x1*x1 + y1*y1 + z1*z1;
  float mx = -2.f*x1, my = -2.f*y1, mz = -2.f*z1;

  // peel column 0: d = |p1-p2|^2 = q1 + |p2|^2 - 2<p1,p2>
  float4 c0 = sp[0];
  float d0 = fmaf(mx,c0.x, fmaf(my,c0.y, fmaf(mz,c0.z, c0.w + q1)));
  float m_ = F2C * __builtin_amdgcn_rcpf(fmaxf(d0, EPSC));   // running max (log2 units)
  float L = 1.f, Ax = c0.x, Ay = c0.y, Az = c0.z;

  #pragma unroll 8
  for (int mm=1; mm<CHN; ++mm){
    float4 c = sp[mm];
    float d = fmaf(mx,c.x, fmaf(my,c.y, fmaf(mz,c.z, c.w + q1)));
    float dinv = __builtin_amdgcn_rcpf(fmaxf(d, EPSC));
    float t = fmaf(F2C, dinv, -m_);              // s - m
    if (__any(t > 0.f)){                         // wave-uniform rescale (rare)
      float tp = fmaxf(t, 0.f);
      float sc = FEXP2(-tp);
      L *= sc; Ax *= sc; Ay *= sc; Az *= sc;
      m_ += tp;
      t = fminf(t, 0.f);                         // s - m_new
    }
    float pe = FEXP2(t);
    L += pe;
    Ax = fmaf(pe,c.x,Ax); Ay = fmaf(pe,c.y,Ay); Az = fmaf(pe,c.z,Az);
  }
  float* pp = part + ((size_t)(b*NC + chunk)*5)*NPTS + n;
  pp[0]=m_; pp[NPTS]=L; pp[2*NPTS]=Ax; pp[3*NPTS]=Ay; pp[4*NPTS]=Az;
}

// merge chunk partials -> pc_nearest + dist; per-block partial stats sums.
template<int NC>
__global__ void __launch_bounds__(512) k_merge(const float* __restrict__ pc1,
                                               const float* __restrict__ part,
                                               float* __restrict__ pcn,
                                               float* __restrict__ dist,
                                               float* __restrict__ psum13){
  int b = blockIdx.x >> 4, rb = blockIdx.x & 15;                    // 128 blocks
  int t = threadIdx.x & 255, half = threadIdx.x >> 8;
  int n = rb*256 + t;
  constexpr int H = NC/2;
  float sc[H], Lc[H], Axc[H], Ayc[H], Azc[H];
  float S = -3.4e38f;
  #pragma unroll
  for (int c=0;c<H;c++){
    const float* pp = part + ((size_t)(b*NC + half*H + c)*5)*NPTS + n;
    sc[c]=pp[0]; Lc[c]=pp[NPTS]; Axc[c]=pp[2*NPTS]; Ayc[c]=pp[3*NPTS]; Azc[c]=pp[4*NPTS];
    S = fmaxf(S, sc[c]);
  }
  float L=0.f, Ax=0.f, Ay=0.f, Az=0.f;
  #pragma unroll
  for (int c=0;c<H;c++){
    float w = FEXP2(sc[c]-S);
    L=fmaf(w,Lc[c],L); Ax=fmaf(w,Axc[c],Ax); Ay=fmaf(w,Ayc[c],Ay); Az=fmaf(w,Azc[c],Az);
  }
  __shared__ float ex[256][5];
  if (half==1){ ex[t][0]=S; ex[t][1]=L; ex[t][2]=Ax; ex[t][3]=Ay; ex[t][4]=Az; }
  __syncthreads();
  __shared__ float red[4][13];
  if (half==0){
    float S1=ex[t][0];
    float M = fmaxf(S,S1);
    float w0=FEXP2(S-M), w1=FEXP2(S1-M);
    L = w0*L + w1*ex[t][1];
    Ax = w0*Ax + w1*ex[t][2];
    Ay = w0*Ay + w1*ex[t][3];
    Az = w0*Az + w1*ex[t][4];
    float inv = 1.f/L;
    float px=Ax*inv, py=Ay*inv, pz=Az*inv;
    const float* p1 = pc1 + (size_t)b*4*NPTS + n;
    float x1=p1[0], y1=p1[NPTS], z1=p1[2*NPTS];
    float dx=x1-px, dy=y1-py, dz=z1-pz;
    float dd=sqrtf(dx*dx+dy*dy+dz*dz);
    pcn[(size_t)(b*3+0)*NPTS+n]=px;
    pcn[(size_t)(b*3+1)*NPTS+n]=py;
    pcn[(size_t)(b*3+2)*NPTS+n]=pz;
    dist[(size_t)b*NPTS+n]=dd;
    float acc[13]={x1,y1,z1,x1*x1,y1*y1,z1*z1,px,py,pz,px*px,py*py,pz*pz,dd};
    int lane = t & 63, wv = t >> 6;
    #pragma unroll
    for (int k=0;k<13;k++){
      float v = acc[k];
      v += __shfl_xor(v,32); v += __shfl_xor(v,16); v += __shfl_xor(v,8);
      v += __shfl_xor(v,4);  v += __shfl_xor(v,2);  v += __shfl_xor(v,1);
      if (lane==0) red[wv][k]=v;
    }
  }
  __syncthreads();
  if (threadIdx.x<13)
    psum13[(size_t)blockIdx.x*13 + threadIdx.x] =
      red[0][threadIdx.x]+red[1][threadIdx.x]+red[2][threadIdx.x]+red[3][threadIdx.x];
}

__device__ __forceinline__ float elemA(const float* S, int i, int k){
  int bi=i>>2, bj=k>>2;
  int ii=i&3, jj=k&3;
  int lo = ii<jj?ii:jj, hi = ii<jj?jj:ii;
  int pe = 4*lo - ((lo*(lo-1))>>1) + (hi-lo);        // sym 4x4 -> 10 idx
  int w;
  if (bi==bj) w = (bi==2)?30:0;
  else {
    int blo = bi<bj?bi:bj, bhi = bi<bj?bj:bi;
    if (blo==0 && bhi==1) return 0.f;                // A01 block is zero
    w = (blo==0)?10:20;                              // (0,2)->wB, (1,2)->wC
  }
  return S[w+pe];
}

// fused per-sample: stats -> M^T M accumulation -> register inverse-power eigensolve -> compose
__global__ void __launch_bounds__(256) k_solve(const float* __restrict__ pc1,
                                               const float* __restrict__ pcn,
                                               const float* __restrict__ dist,
                                               const float* __restrict__ psum13,
                                               float* __restrict__ out){
  int b=blockIdx.x, t=threadIdx.x;                   // 8 blocks x 4 waves
  __shared__ float stot[13];
  __shared__ float sst[13];
  if (t<13){
    float s=0.f;
    #pragma unroll
    for (int i=0;i<16;i++) s += psum13[(size_t)(b*16+i)*13 + t];
    stot[t]=s;
  }
  __syncthreads();
  if (t==0){
    const float Nf = 4096.f, Nm1 = 4095.f;
    #pragma unroll
    for (int j=0;j<3;j++){
      float m  = stot[j]/Nf;
      float v  = (stot[3+j]-Nf*m*m)/Nm1;             // ddof=1
      sst[j]=m; sst[3+j]=sqrtf(fmaxf(v,0.f));
      float m2 = stot[6+j]/Nf;
      float v2 = (stot[9+j]-Nf*m2*m2)/Nm1;
      sst[6+j]=m2; sst[9+j]=sqrtf(fmaxf(v2,0.f));
    }
    sst[12]=stot[12]/Nf;
  }
  __syncthreads();
  float i1x=1.f/sst[3], i1y=1.f/sst[4], i1z=1.f/sst[5];
  float t1x=-sst[0]/sst[3], t1y=-sst[1]/sst[4], t1z=-sst[2]/sst[5];
  float i2x=1.f/sst[9], i2y=1.f/sst[10], i2z=1.f/sst[11];
  float t2x=-sst[6]/sst[9], t2y=-sst[7]/sst[10], t2z=-sst[8]/sst[11];
  float meanD=sst[12];

  float acc[40];
  #pragma unroll
  for (int k=0;k<40;k++) acc[k]=0.f;
  #pragma unroll 4
  for (int i=0;i<16;i++){
    int n=i*256+t;
    const float* p1 = pc1 + (size_t)b*4*NPTS + n;
    float X1=fmaf(p1[0],i1x,t1x), Y1=fmaf(p1[NPTS],i1y,t1y), Z1=fmaf(p1[2*NPTS],i1z,t1z);
    float X2=fmaf(pcn[(size_t)(b*3+0)*NPTS+n],i2x,t2x);
    float Y2=fmaf(pcn[(size_t)(b*3+1)*NPTS+n],i2y,t2y);
    float Z2=fmaf(pcn[(size_t)(b*3+2)*NPTS+n],i2z,t2z);
    // sigmoid((dist-mean-EPS)*-1e10) > 0.5  <=>  (dist-mean)-EPS < 0
    float zthr = (dist[(size_t)b*NPTS+n] - meanD) - EPSC;
    float msk = (zthr < 0.f) ? 1.f : 0.f;
    float tz = msk*Z2;
    float wA = tz*Z2, wB = -tz*X2, wC = -tz*Y2;
    float wD = msk*fmaf(X2,X2,Y2*Y2);
    float ee[10]={X1*X1, X1*Y1, X1*Z1, X1, Y1*Y1, Y1*Z1, Y1, Z1*Z1, Z1, 1.f};
    #pragma unroll
    for (int j=0;j<10;j++){
      acc[j]    = fmaf(wA,ee[j],acc[j]);
      acc[10+j] = fmaf(wB,ee[j],acc[10+j]);
      acc[20+j] = fmaf(wC,ee[j],acc[20+j]);
      acc[30+j] = fmaf(wD,ee[j],acc[30+j]);
    }
  }
  __shared__ float red[4][40];
  __shared__ float SS[40];
  {
    int lane=t&63, wv=t>>6;
    #pragma unroll
    for (int k=0;k<40;k++){
      float v=acc[k];
      v+=__shfl_xor(v,32); v+=__shfl_xor(v,16); v+=__shfl_xor(v,8);
      v+=__shfl_xor(v,4);  v+=__shfl_xor(v,2);  v+=__shfl_xor(v,1);
      if(lane==0) red[wv][k]=v;
    }
  }
  __syncthreads();
  if (t<40) SS[t]=red[0][t]+red[1][t]+red[2][t]+red[3][t];
  __syncthreads();

  if (t<64){
    // ---- register-resident inverse-power eigensolve (wave 0, lanes 0..11 carry data) ----
    // every lane redundantly: packed A (lower-tri, 78), ridge, Cholesky
    float a[78];
    #pragma unroll
    for (int i=0;i<12;i++)
      #pragma unroll
      for (int j=0;j<=i;j++)
        a[IDX(i,j)] = elemA(SS,i,j);
    {
      float tr=0.f;
      #pragma unroll
      for (int i=0;i<12;i++) tr += a[IDX(i,i)];
      float eps = 1e-5f * tr * (1.f/12.f);           // uniform shift: eigvecs unchanged
      #pragma unroll
      for (int i=0;i<12;i++) a[IDX(i,i)] += eps;
    }
    #pragma unroll
    for (int j=0;j<12;j++){
      float s = a[IDX(j,j)];
      #pragma unroll
      for (int k=0;k<j;k++) s = fmaf(-a[IDX(j,k)], a[IDX(j,k)], s);
      float d = sqrtf(fmaxf(s, 1e-30f));
      a[IDX(j,j)] = d;
      float dinv = __builtin_amdgcn_rcpf(d);
      #pragma unroll
      for (int i=j+1;i<12;i++){
        float s2 = a[IDX(i,j)];
        #pragma unroll
        for (int k=0;k<j;k++) s2 = fmaf(-a[IDX(i,k)], a[IDX(j,k)], s2);
        a[IDX(i,j)] = s2 * dinv;
      }
    }
    // lane j: solve (A+eps I) x = e_j  ->  column j of B (symmetric -> row j)
    float y[12], Brow[12];
    #pragma unroll
    for (int i=0;i<12;i++){
      float s = (i==t) ? 1.f : 0.f;
      #pragma unroll
      for (int k=0;k<i;k++) s = fmaf(-a[IDX(i,k)], y[k], s);
      y[i] = s * __builtin_amdgcn_rcpf(a[IDX(i,i)]);
    }
    #pragma unroll
    for (int i=11;i>=0;i--){
      float s = y[i];
      #pragma unroll
      for (int k=11;k>i;k--) s = fmaf(-a[IDX(k,i)], Brow[k], s);
      Brow[i] = s * __builtin_amdgcn_rcpf(a[IDX(i,i)]);
    }
    // scale so ||B||_max ~ 1 (eigvecs unchanged)
    {
      float mxv = 0.f;
      #pragma unroll
      for (int i=0;i<12;i++) mxv = fmaxf(mxv, fabsf(Brow[i]));
      mxv = fmaxf(mxv, __shfl_xor(mxv,1)); mxv = fmaxf(mxv, __shfl_xor(mxv,2));
      mxv = fmaxf(mxv, __shfl_xor(mxv,4)); mxv = fmaxf(mxv, __shfl_xor(mxv,8));
      float sc = __builtin_amdgcn_rcpf(mxv);
      #pragma unroll
      for (int i=0;i<12;i++) Brow[i] *= sc;
    }
    // square twice: B -> B^2 -> B^4 (symmetric each time), rescaled
    #pragma unroll
    for (int rep=0; rep<2; ++rep){
      float nr[12];
      #pragma unroll
      for (int i=0;i<12;i++) nr[i]=0.f;
      #pragma unroll
      for (int k=0;k<12;k++){
        float bjk = Brow[k];
        #pragma unroll
        for (int m2=0;m2<12;m2++){
          float bkm = __shfl(Brow[m2], k);
          nr[m2] = fmaf(bjk, bkm, nr[m2]);
        }
      }
      float mxv = 0.f;
      #pragma unroll
      for (int i=0;i<12;i++) mxv = fmaxf(mxv, fabsf(nr[i]));
      mxv = fmaxf(mxv, __shfl_xor(mxv,1)); mxv = fmaxf(mxv, __shfl_xor(mxv,2));
      mxv = fmaxf(mxv, __shfl_xor(mxv,4)); mxv = fmaxf(mxv, __shfl_xor(mxv,8));
      float sc = __builtin_amdgcn_rcpf(mxv);
      #pragma unroll
      for (int i=0;i<12;i++) Brow[i] = nr[i]*sc;
    }
    // power iteration on B^4: v0 = B^4 * 1, then 14 iters (total ~ A^-60)
    float v = 0.f;
    #pragma unroll
    for (int i=0;i<12;i++) v += Brow[i];
    #pragma unroll
    for (int it=0; it<14; ++it){
      float w = 0.f;
      #pragma unroll
      for (int k=0;k<12;k++) w = fmaf(Brow[k], __shfl(v,k), w);
      float nn = w*w;
      nn += __shfl_xor(nn,1); nn += __shfl_xor(nn,2);
      nn += __shfl_xor(nn,4); nn += __shfl_xor(nn,8);
      v = w * rsqrtf(nn);
    }
    float pvf[12];
    #pragma unroll
    for (int i=0;i<12;i++) pvf[i] = __shfl(v, i);

    if (t==0){
      double pv[12];
      #pragma unroll
      for (int i=0;i<12;i++) pv[i]=(double)pvf[i];
      if (pv[10]<0.0){
        #pragma unroll
        for (int i=0;i<12;i++) pv[i]=-pv[i];
      }
      double nrm = sqrt(pv[8]*pv[8]+pv[9]*pv[9]+pv[10]*pv[10]);
      #pragma unroll
      for (int i=0;i<12;i++) pv[i]/=nrm;
      double m1[3]={sst[0],sst[1],sst[2]}, sd1[3]={sst[3],sst[4],sst[5]};
      double m2[3]={sst[6],sst[7],sst[8]}, sd2[3]={sst[9],sst[10],sst[11]};
      double Td[3][4]={{pv[0],pv[1],pv[2],pv[3]},
                       {pv[4],pv[5],pv[6],pv[7]},
                       {pv[8],pv[9],pv[10],pv[11]}};
      double F[3][4];
      for (int i=0;i<3;i++){
        double b3 = Td[i][3];
        for (int j=0;j<3;j++){
          F[i][j] = sd2[i]*(Td[i][j]/sd1[j]);        // inv(T2) @ Tdlt @ T1
          b3 += Td[i][j]*(-m1[j]/sd1[j]);
        }
        F[i][3] = sd2[i]*b3 + m2[i];
      }
      double zx=F[0][2],zy=F[1][2],zz2=F[2][2];
      double zn=sqrt(zx*zx+zy*zy+zz2*zz2);
      zx/=zn; zy/=zn; zz2/=zn;
      double yx=F[0][1],yy=F[1][1],yz=F[2][1];
      double xx=yy*zz2-yz*zy, xy=yz*zx-yx*zz2, xz=yx*zy-yy*zx;
      double xn=sqrt(xx*xx+xy*xy+xz*xz);
      xx/=xn; xy/=xn; xz/=xn;
      double y2x=zy*xz-zz2*xy, y2y=zz2*xx-zx*xz, y2z=zx*xy-zy*xx;
      double R00=xx,R01=y2x,R02=zx;
      double R10=xy,R11=y2y,R12=zy;
      double R20=xz,R21=y2z,R22=zz2;
      float* oT = out + b*16;
      oT[0]=(float)R00; oT[1]=(float)R01; oT[2]=(float)R02; oT[3]=(float)F[0][3];
      oT[4]=(float)R10; oT[5]=(float)R11; oT[6]=(float)R12; oT[7]=(float)F[1][3];
      oT[8]=(float)R20; oT[9]=(float)R21; oT[10]=(float)R22; oT[11]=(float)F[2][3];
      oT[12]=0.f; oT[13]=0.f; oT[14]=0.f; oT[15]=1.f;
      double qw=0.5*sqrt(fmax(1e-12, 1.0+R00+R11+R22));
      double qx=0.5*sqrt(fmax(0.0, 1.0+R00-R11-R22));
      double qy=0.5*sqrt(fmax(0.0, 1.0-R00+R11-R22));
      double qz=0.5*sqrt(fmax(0.0, 1.0-R00-R11+R22));
      if (R21-R12<0.0) qx=-qx;
      if (R02-R20<0.0) qy=-qy;
      if (R10-R01<0.0) qz=-qz;
      float* oQ = out + 128 + b*4;
      oQ[0]=(float)qw; oQ[1]=(float)qx; oQ[2]=(float)qy; oQ[3]=(float)qz;
      float* ot3 = out + 160 + b*3;
      ot3[0]=(float)F[0][3]; ot3[1]=(float)F[1][3]; ot3[2]=(float)F[2][3];
    }
  }
}

extern "C" void kernel_launch(void* const* d_in, const int* in_sizes, int n_in,
                              void* d_out, int out_size, void* d_ws, size_t ws_size,
                              hipStream_t stream) {
  const float* pc1 = (const float*)d_in[0];
  const float* pc2 = (const float*)d_in[1];
  float* out  = (float*)d_out;
  float* ws   = (float*)d_ws;

  // NC=16 (2048 blocks) if ws allows (~11 MB), else NC=8
  const size_t fixed = 98304 + 32768 + 128*13;
  size_t need16 = ((size_t)8*16*5*NPTS + fixed) * 4;
  int NC = (ws_size >= need16) ? 16 : 8;

  float* part  = ws;                                  // 8*NC*5*4096
  float* pcn   = part + (size_t)8*NC*5*NPTS;          // 98304
  float* dist  = pcn + 98304;                         // 32768
  float* psum13= dist + 32768;                        // 1664

  if (NC == 16){
    hipLaunchKernelGGL(k_soft<256>,  dim3(2048), dim3(256), 0, stream, pc1, pc2, part);
    hipLaunchKernelGGL(k_merge<16>,  dim3(128),  dim3(512), 0, stream, pc1, part, pcn, dist, psum13);
  } else {
    hipLaunchKernelGGL(k_soft<512>,  dim3(1024), dim3(256), 0, stream, pc1, pc2, part);
    hipLaunchKernelGGL(k_merge<8>,   dim3(128),  dim3(512), 0, stream, pc1, part, pcn, dist, psum13);
  }
  hipLaunchKernelGGL(k_solve, dim3(8), dim3(256), 0, stream, pc1, pcn, dist, psum13, out);
}